// Round 3
// baseline (886.707 us; speedup 1.0000x reference)
//
#include <hip/hip_runtime.h>
#include <hip/hip_bf16.h>
#include <stdint.h>

#define NN 4096
#define H4 4

__device__ __forceinline__ float lrelu(float z) { return z > 0.f ? z : 0.2f * z; }

// ---------------- adj -> 64-bit row masks ----------------
__global__ __launch_bounds__(256) void k_mask(const int* __restrict__ adj,
                                              unsigned long long* __restrict__ mask) {
  int row = blockIdx.x, tid = threadIdx.x;
  int lane = tid & 63, wv = tid >> 6;
  const int* arow = adj + (size_t)row * NN;
  for (int c = 0; c < NN; c += 256) {
    int col = c + wv * 64 + lane;
    unsigned long long b = __ballot(arow[col] != 0);
    if (lane == 0) mask[row * 64 + (c >> 6) + wv] = b;
  }
}

// ---------------- tiled GEMM: C[M,N] = A[M,K] @ B[K,N] (+bias), all f32 ----------------
__global__ __launch_bounds__(256) void k_gemm(const float* __restrict__ A,
                                              const float* __restrict__ B,
                                              const float* __restrict__ bias,
                                              float* __restrict__ C, int M, int K, int Nc) {
  __shared__ float As[16][68];  // [k][m], stride 68 floats (272B: 16B-multiple, conflict-free)
  __shared__ float Bs[16][68];  // [k][n]
  int tid = threadIdx.x;
  int tx = tid & 15, ty = tid >> 4;
  int mBase = blockIdx.y * 64, nBase = blockIdx.x * 64;
  float acc[4][4] = {};
  for (int k0 = 0; k0 < K; k0 += 16) {
#pragma unroll
    for (int l = 0; l < 4; ++l) {
      int idx = l * 256 + tid;
      int m = idx >> 4, k = idx & 15;
      As[k][m] = A[(size_t)(mBase + m) * K + (k0 + k)];
    }
#pragma unroll
    for (int l = 0; l < 4; ++l) {
      int idx = l * 256 + tid;
      int k = idx >> 6, n = idx & 63;
      int gn = nBase + n;
      Bs[k][n] = (gn < Nc) ? B[(size_t)(k0 + k) * Nc + gn] : 0.f;
    }
    __syncthreads();
#pragma unroll
    for (int k = 0; k < 16; ++k) {
      float4 a = *(const float4*)&As[k][ty * 4];
      float4 b = *(const float4*)&Bs[k][tx * 4];
      float av[4] = {a.x, a.y, a.z, a.w};
      float bv[4] = {b.x, b.y, b.z, b.w};
#pragma unroll
      for (int r = 0; r < 4; ++r)
#pragma unroll
        for (int c = 0; c < 4; ++c) acc[r][c] += av[r] * bv[c];
    }
    __syncthreads();
  }
#pragma unroll
  for (int r = 0; r < 4; ++r) {
    int gm = mBase + ty * 4 + r;
#pragma unroll
    for (int c = 0; c < 4; ++c) {
      int gn = nBase + tx * 4 + c;
      if (gn < Nc) {
        float v = acc[r][c];
        if (bias) v += bias[gn];
        C[(size_t)gm * Nc + gn] = v;
      }
    }
  }
}

// ---------------- attention scores: es[h][n], ed[h][n] ----------------
template <int F>
__global__ __launch_bounds__(256) void k_scores(const float* __restrict__ h,
                                                const float* __restrict__ a_s,
                                                const float* __restrict__ a_d,
                                                float* __restrict__ es, float* __restrict__ ed) {
  int idx = blockIdx.x * 256 + threadIdx.x;
  if (idx >= NN * H4) return;
  int n = idx >> 2, hd = idx & 3;
  const float* hp = h + (size_t)n * (H4 * F) + hd * F;
  const float* sp = a_s + hd * F;
  const float* dp = a_d + hd * F;
  float ss = 0.f, sd = 0.f;
#pragma unroll 4
  for (int f = 0; f < F; ++f) {
    float v = hp[f];
    ss += v * sp[f];
    sd += v * dp[f];
  }
  es[hd * NN + n] = ss;
  ed[hd * NN + n] = sd;
}

// ---------------- masked-softmax stats: m[h][i], 1/l[h][i] ----------------
// one wave per (i, head): max over masked j of ed (lrelu monotone => row max), then sum of exp.
// Invariant: z = lrelu(esi+ed_j) <= me exactly in fp (monotone add + monotone lrelu), so
// exp args are <= 0 with NO clamps — any NaN upstream stays visible.
__global__ __launch_bounds__(256) void k_stats(const float* __restrict__ es,
                                               const float* __restrict__ ed,
                                               const unsigned long long* __restrict__ mask,
                                               float* __restrict__ mout, float* __restrict__ linv) {
  int i = blockIdx.x, tid = threadIdx.x;
  int hd = tid >> 6, lane = tid & 63;
  const unsigned long long* mrow = mask + (size_t)i * 64;
  const float* edh = ed + hd * NN;
  float esi = es[hd * NN + i];
  float mx = -1e30f;
  for (int c = 0; c < 64; ++c) {
    unsigned long long w = mrow[c];
    float v = edh[c * 64 + lane];
    if ((w >> lane) & 1ull) mx = fmaxf(mx, v);
  }
#pragma unroll
  for (int off = 32; off; off >>= 1) mx = fmaxf(mx, __shfl_xor(mx, off, 64));
  float me = lrelu(esi + mx);
  float s = 0.f;
  for (int c = 0; c < 64; ++c) {
    unsigned long long w = mrow[c];
    float z = lrelu(esi + edh[c * 64 + lane]);
    float e = __expf(z - me);
    if ((w >> lane) & 1ull) s += e;
  }
#pragma unroll
  for (int off = 32; off; off >>= 1) s += __shfl_xor(s, off, 64);
  if (lane == 0) {
    mout[hd * NN + i] = me;
    linv[hd * NN + i] = (s > 0.f) ? 1.f / s : 0.f;
  }
}

// ---------------- aggregation: out[i, hd*F+f] = sum_j w(i,j) * h[j, hd*F+f] ----------------
template <int F, int TI, int RPT, int WSTR>
__global__ __launch_bounds__(256) void k_agg(const float* __restrict__ hbuf,
                                             const float* __restrict__ es,
                                             const float* __restrict__ ed,
                                             const float* __restrict__ mrowv,
                                             const float* __restrict__ linv,
                                             const unsigned long long* __restrict__ mask,
                                             float* __restrict__ out) {
  constexpr int CG = F / 4;     // col groups of 4
  constexpr int RG = 256 / CG;  // row groups
  static_assert(RG * RPT == TI, "tile mismatch");
  __shared__ float Hc[64][F];     // h chunk, [j][f]
  __shared__ float Wt[64][WSTR];  // weights, [j][i] padded
  __shared__ float s_es[TI], s_m[TI], s_li[TI];
  int tid = threadIdx.x;
  int hd = blockIdx.y;
  int i0 = blockIdx.x * TI;
  if (tid < TI) {
    s_es[tid] = es[hd * NN + i0 + tid];
    s_m[tid] = mrowv[hd * NN + i0 + tid];
    s_li[tid] = linv[hd * NN + i0 + tid];
  }
  __syncthreads();
  int cg = tid % CG, rg = tid / CG;
  int c0 = cg * 4;
  int irow = rg * RPT;
  int wj = tid & 63;   // j within chunk (weight phase)
  int wib = tid >> 6;  // 0..3
  float acc[RPT][4] = {};
  for (int jc = 0; jc < NN / 64; ++jc) {
    int j0 = jc * 64;
    // stage h chunk (coalesced float4)
    constexpr int VL = (64 * F) / (4 * 256);
#pragma unroll
    for (int l = 0; l < VL; ++l) {
      int v = l * 256 + tid;
      int f4 = v % (F / 4), jj = v / (F / 4);
      *(float4*)&Hc[jj][f4 * 4] =
          *(const float4*)&hbuf[(size_t)(j0 + jj) * (H4 * F) + hd * F + f4 * 4];
    }
    // compute softmax weights for this chunk
    float edv = ed[hd * NN + j0 + wj];
#pragma unroll
    for (int r = 0; r < TI / 4; ++r) {
      int i = wib + r * 4;
      unsigned long long w = mask[(size_t)(i0 + i) * 64 + jc];
      float wt = 0.f;
      if ((w >> wj) & 1ull) {
        float z = lrelu(s_es[i] + edv);
        wt = __expf(z - s_m[i]) * s_li[i];
      }
      Wt[wj][i] = wt;
    }
    __syncthreads();
#pragma unroll 4
    for (int j = 0; j < 64; ++j) {
      float4 hv = *(const float4*)&Hc[j][c0];
      float wr[RPT];
      if constexpr (RPT == 4) {
        float4 t = *(const float4*)&Wt[j][irow];
        wr[0] = t.x; wr[1] = t.y; wr[2] = t.z; wr[3] = t.w;
      } else {
#pragma unroll
        for (int r = 0; r < RPT; ++r) wr[r] = Wt[j][irow + r];
      }
#pragma unroll
      for (int r = 0; r < RPT; ++r) {
        acc[r][0] += wr[r] * hv.x;
        acc[r][1] += wr[r] * hv.y;
        acc[r][2] += wr[r] * hv.z;
        acc[r][3] += wr[r] * hv.w;
      }
    }
    __syncthreads();
  }
#pragma unroll
  for (int r = 0; r < RPT; ++r) {
    int gi = i0 + irow + r;
    float4 v = make_float4(acc[r][0], acc[r][1], acc[r][2], acc[r][3]);
    *(float4*)&out[(size_t)gi * (H4 * F) + hd * F + c0] = v;
  }
}

// ---------------- per-column mean / inv-std ----------------
__global__ __launch_bounds__(256) void k_colstats(const float* __restrict__ y,
                                                  float* __restrict__ stats, int C) {
  int c = blockIdx.x, tid = threadIdx.x;
  float s = 0.f, s2 = 0.f;
  for (int r = tid; r < NN; r += 256) {
    float v = y[(size_t)r * C + c];
    s += v;
    s2 += v * v;
  }
  __shared__ float sh[256], sh2[256];
  sh[tid] = s; sh2[tid] = s2;
  __syncthreads();
  for (int off = 128; off; off >>= 1) {
    if (tid < off) { sh[tid] += sh[tid + off]; sh2[tid] += sh2[tid + off]; }
    __syncthreads();
  }
  if (tid == 0) {
    float mean = sh[0] * (1.f / NN);
    float var = sh2[0] * (1.f / NN) - mean * mean;
    stats[c] = mean;
    stats[C + c] = rsqrtf(fmaxf(var, 0.f) + 1e-5f);
  }
}

// ---------------- BN + ELU (plain ELU — NaN stays visible) ----------------
__global__ __launch_bounds__(256) void k_bn_elu(const float* __restrict__ y,
                                                const float* __restrict__ stats,
                                                const float* __restrict__ gamma,
                                                const float* __restrict__ beta,
                                                float* __restrict__ o, int C, int total) {
  int idx = blockIdx.x * 256 + threadIdx.x;
  if (idx >= total) return;
  int c = idx % C;
  float v = (y[idx] - stats[c]) * stats[C + c] * gamma[c] + beta[c];
  v = v > 0.f ? v : (__expf(v) - 1.f);
  o[idx] = v;
}

extern "C" void kernel_launch(void* const* d_in, const int* in_sizes, int n_in,
                              void* d_out, int out_size, void* d_ws, size_t ws_size,
                              hipStream_t stream) {
  (void)in_sizes; (void)n_in; (void)out_size; (void)ws_size;
  // Reference dtypes: everything float32 except adj (int32).
  const float* x   = (const float*)d_in[0];
  const int*   adj = (const int*)d_in[1];
  const float* W1  = (const float*)d_in[2];
  const float* a1s = (const float*)d_in[3];
  const float* a1d = (const float*)d_in[4];
  const float* lw1 = (const float*)d_in[5];
  const float* lb1 = (const float*)d_in[6];
  const float* g1  = (const float*)d_in[7];
  const float* be1 = (const float*)d_in[8];
  const float* W2  = (const float*)d_in[9];
  const float* a2s = (const float*)d_in[10];
  const float* a2d = (const float*)d_in[11];
  const float* lw2 = (const float*)d_in[12];
  const float* lb2 = (const float*)d_in[13];
  const float* g2  = (const float*)d_in[14];
  const float* be2 = (const float*)d_in[15];
  float* out = (float*)d_out;

  // ---- workspace layout (~18.6 MB), liveness-checked overlays ----
  char* w = (char*)d_ws;
  const size_t MB = 1u << 20;
  unsigned long long* mask = (unsigned long long*)(w + 0);  // [0,2) whole session
  float* h1 = (float*)(w + 2 * MB);    // [2,10)  8MB; dead after agg1
  float* y1 = (float*)(w + 2 * MB);    // [2,3)   overlay (gemm2 output; h1 dead)
  float* x2 = (float*)(w + 3 * MB);    // [3,4)
  float* h2 = (float*)(w + 4 * MB);    // [4,6)
  float* x1 = (float*)(w + 10 * MB);   // [10,18) 8MB; dead after gemm2
  float* x3 = (float*)(w + 10 * MB);   // [10,12) overlay (agg2 output; x1 dead)
  float* y2 = (float*)(w + 12 * MB);   // [12,12.25)
  float* es1 = (float*)(w + 18 * MB);  // aux: 8 x 64KB + stats
  float* ed1 = es1 + 16384;
  float* m1  = ed1 + 16384;
  float* li1 = m1 + 16384;
  float* es2 = li1 + 16384;
  float* ed2 = es2 + 16384;
  float* m2  = ed2 + 16384;
  float* li2 = m2 + 16384;
  float* st1 = li2 + 16384;
  float* st2 = st1 + 256;

  // adj -> bitmask (shared by both layers)
  k_mask<<<NN, 256, 0, stream>>>(adj, mask);

  // ---- layer 1 GAT ----
  k_gemm<<<dim3(8, 64), 256, 0, stream>>>(x, W1, nullptr, h1, NN, 512, 512);
  k_scores<128><<<(NN * H4) / 256, 256, 0, stream>>>(h1, a1s, a1d, es1, ed1);
  k_stats<<<NN, 256, 0, stream>>>(es1, ed1, mask, m1, li1);
  k_agg<128, 32, 4, 36><<<dim3(NN / 32, H4), 256, 0, stream>>>(h1, es1, ed1, m1, li1, mask, x1);

  // ---- linear + BN + ELU ----
  k_gemm<<<dim3(1, 64), 256, 0, stream>>>(x1, lw1, lb1, y1, NN, 512, 64);
  k_colstats<<<64, 256, 0, stream>>>(y1, st1, 64);
  k_bn_elu<<<(NN * 64) / 256, 256, 0, stream>>>(y1, st1, g1, be1, x2, 64, NN * 64);

  // ---- layer 2 GAT ----
  k_gemm<<<dim3(2, 64), 256, 0, stream>>>(x2, W2, nullptr, h2, NN, 64, 128);
  k_scores<32><<<(NN * H4) / 256, 256, 0, stream>>>(h2, a2s, a2d, es2, ed2);
  k_stats<<<NN, 256, 0, stream>>>(es2, ed2, mask, m2, li2);
  k_agg<32, 32, 1, 33><<<dim3(NN / 32, H4), 256, 0, stream>>>(h2, es2, ed2, m2, li2, mask, x3);

  // ---- final linear + BN + ELU ----
  k_gemm<<<dim3(1, 64), 256, 0, stream>>>(x3, lw2, lb2, y2, NN, 128, 16);
  k_colstats<<<16, 256, 0, stream>>>(y2, st2, 16);
  k_bn_elu<<<(NN * 16) / 256, 256, 0, stream>>>(y2, st2, g2, be2, out, 16, NN * 16);
}

// Round 4
// 561.124 us; speedup vs baseline: 1.5802x; 1.5802x over previous
//
#include <hip/hip_runtime.h>
#include <hip/hip_bf16.h>
#include <stdint.h>

#define NN 4096
#define H4 4

typedef __hip_bfloat16 bf16;
typedef unsigned short ushort_t;
typedef unsigned long long ull_t;
typedef __attribute__((ext_vector_type(4))) float f32x4;
typedef __attribute__((ext_vector_type(8))) short s16x8;

__device__ __forceinline__ float cvt(float v) { return v; }
__device__ __forceinline__ float cvt(bf16 v) { return __bfloat162float(v); }
__device__ __forceinline__ float lrelu(float z) { return z > 0.f ? z : 0.2f * z; }
__device__ __forceinline__ void sto(float* p, float v) { *p = v; }
__device__ __forceinline__ void sto(bf16* p, float v) { *p = __float2bfloat16(v); }
// f32 -> bf16 RNE bit-trick
__device__ __forceinline__ ushort_t f2bf(float f) {
  unsigned u = __float_as_uint(f);
  return (ushort_t)((u + 0x7fff + ((u >> 16) & 1)) >> 16);
}

// ---------------- adj -> 64-bit row masks ----------------
__global__ __launch_bounds__(256) void k_mask(const int* __restrict__ adj,
                                              ull_t* __restrict__ mask) {
  int row = blockIdx.x, tid = threadIdx.x;
  int lane = tid & 63, wv = tid >> 6;
  const int* arow = adj + (size_t)row * NN;
  for (int c = 0; c < NN; c += 256) {
    int col = c + wv * 64 + lane;
    ull_t b = __ballot(arow[col] != 0);
    if (lane == 0) mask[row * 64 + (c >> 6) + wv] = b;
  }
}

// ---------------- tiled GEMM: C[M,N] = A[M,K] @ B[K,N] (+bias) ----------------
template <typename TA>
__global__ __launch_bounds__(256) void k_gemm(const TA* __restrict__ A,
                                              const float* __restrict__ B,
                                              const float* __restrict__ bias,
                                              float* __restrict__ C, int M, int K, int Nc) {
  __shared__ float As[16][68];
  __shared__ float Bs[16][68];
  int tid = threadIdx.x;
  int tx = tid & 15, ty = tid >> 4;
  int mBase = blockIdx.y * 64, nBase = blockIdx.x * 64;
  float acc[4][4] = {};
  for (int k0 = 0; k0 < K; k0 += 16) {
#pragma unroll
    for (int l = 0; l < 4; ++l) {
      int idx = l * 256 + tid;
      int m = idx >> 4, k = idx & 15;
      As[k][m] = cvt(A[(size_t)(mBase + m) * K + (k0 + k)]);
    }
#pragma unroll
    for (int l = 0; l < 4; ++l) {
      int idx = l * 256 + tid;
      int k = idx >> 6, n = idx & 63;
      int gn = nBase + n;
      Bs[k][n] = (gn < Nc) ? B[(size_t)(k0 + k) * Nc + gn] : 0.f;
    }
    __syncthreads();
#pragma unroll
    for (int k = 0; k < 16; ++k) {
      float4 a = *(const float4*)&As[k][ty * 4];
      float4 b = *(const float4*)&Bs[k][tx * 4];
      float av[4] = {a.x, a.y, a.z, a.w};
      float bv[4] = {b.x, b.y, b.z, b.w};
#pragma unroll
      for (int r = 0; r < 4; ++r)
#pragma unroll
        for (int c = 0; c < 4; ++c) acc[r][c] += av[r] * bv[c];
    }
    __syncthreads();
  }
#pragma unroll
  for (int r = 0; r < 4; ++r) {
    int gm = mBase + ty * 4 + r;
#pragma unroll
    for (int c = 0; c < 4; ++c) {
      int gn = nBase + tx * 4 + c;
      if (gn < Nc) {
        float v = acc[r][c];
        if (bias) v += bias[gn];
        C[(size_t)gm * Nc + gn] = v;
      }
    }
  }
}

// ---------------- h[N][FT] f32 -> hT[FT][N] bf16 (per-head slices are contiguous) --------
template <int FT>
__global__ __launch_bounds__(256) void k_transpose(const float* __restrict__ h,
                                                   ushort_t* __restrict__ hT) {
  int t = threadIdx.x;
  int j = (blockIdx.x << 6) + (t & 63);
  int f0 = blockIdx.y * 16 + (t >> 6) * 4;
  float4 v = *(const float4*)&h[(size_t)j * FT + f0];
  hT[(size_t)(f0 + 0) * NN + j] = f2bf(v.x);
  hT[(size_t)(f0 + 1) * NN + j] = f2bf(v.y);
  hT[(size_t)(f0 + 2) * NN + j] = f2bf(v.z);
  hT[(size_t)(f0 + 3) * NN + j] = f2bf(v.w);
}

// ---------------- attention scores ----------------
template <int F>
__global__ __launch_bounds__(256) void k_scores(const float* __restrict__ h,
                                                const float* __restrict__ a_s,
                                                const float* __restrict__ a_d,
                                                float* __restrict__ es, float* __restrict__ ed) {
  int idx = blockIdx.x * 256 + threadIdx.x;
  if (idx >= NN * H4) return;
  int n = idx >> 2, hd = idx & 3;
  const float* hp = h + (size_t)n * (H4 * F) + hd * F;
  const float* sp = a_s + hd * F;
  const float* dp = a_d + hd * F;
  float ss = 0.f, sd = 0.f;
#pragma unroll 4
  for (int f = 0; f < F; ++f) {
    float v = hp[f];
    ss += v * sp[f];
    sd += v * dp[f];
  }
  es[hd * NN + n] = ss;
  ed[hd * NN + n] = sd;
}

// ---------------- masked-softmax stats (exact fp invariant: z <= me, no clamps) --------
__global__ __launch_bounds__(256) void k_stats(const float* __restrict__ es,
                                               const float* __restrict__ ed,
                                               const ull_t* __restrict__ mask,
                                               float* __restrict__ mout, float* __restrict__ linv) {
  int i = blockIdx.x, tid = threadIdx.x;
  int hd = tid >> 6, lane = tid & 63;
  const ull_t* mrow = mask + (size_t)i * 64;
  const float* edh = ed + hd * NN;
  float esi = es[hd * NN + i];
  float mx = -1e30f;
  for (int c = 0; c < 64; ++c) {
    ull_t w = mrow[c];
    float v = edh[c * 64 + lane];
    if ((w >> lane) & 1ull) mx = fmaxf(mx, v);
  }
#pragma unroll
  for (int off = 32; off; off >>= 1) mx = fmaxf(mx, __shfl_xor(mx, off, 64));
  float me = lrelu(esi + mx);
  float s = 0.f;
  for (int c = 0; c < 64; ++c) {
    ull_t w = mrow[c];
    float z = lrelu(esi + edh[c * 64 + lane]);
    float e = __expf(z - me);
    if ((w >> lane) & 1ull) s += e;
  }
#pragma unroll
  for (int off = 32; off; off >>= 1) s += __shfl_xor(s, off, 64);
  if (lane == 0) {
    mout[hd * NN + i] = me;
    linv[hd * NN + i] = (s > 0.f) ? 1.f / s : 0.f;
  }
}

// ---------------- MFMA aggregation: out[i, hd*F+f] = sum_j P(i,j) * h[j, hd*F+f] --------
// Block: 64-row i-tile, one head, 256 thr = 4 waves. Per 64-j chunk:
//   stage B = hT chunk (bf16 [f][j], k-contig) + generate A = P (bf16 [i][j]) in LDS,
//   then v_mfma_f32_16x16x32_bf16. Rows padded to 72 ushorts (144B): 16B-aligned b128,
//   uniform bank load (bank-quad = (row+quad)%8).
// Wave tiling: rows r0=(w&1)*32 (2 row-tiles), cols c0=(w>>1)*COL_T*16 (COL_T col-tiles).
template <int F, int COL_T, typename TO>
__global__ __launch_bounds__(256) void k_agg_mfma(
    const ushort_t* __restrict__ hT, const float* __restrict__ es,
    const float* __restrict__ ed, const float* __restrict__ mrowv,
    const float* __restrict__ linv, const ull_t* __restrict__ mask,
    TO* __restrict__ out) {
  constexpr int BOFF = 64 * 72;  // A buffer: 64 rows; B buffer: F rows
  __shared__ ushort_t lds[BOFF + F * 72];
  int t = threadIdx.x;
  int w = t >> 6, lane = t & 63;
  int q = lane >> 4, nn = lane & 15;
  int hd = blockIdx.y;
  int i0 = blockIdx.x * 64;
  int wi = t >> 3, jg = t & 7;  // weight-gen / staging mapping

  // per-thread softmax row stats for rows (i0+wi) and (i0+32+wi)
  float esA = es[hd * NN + i0 + wi], mA = mrowv[hd * NN + i0 + wi], liA = linv[hd * NN + i0 + wi];
  float esB = es[hd * NN + i0 + 32 + wi], mB = mrowv[hd * NN + i0 + 32 + wi],
        liB = linv[hd * NN + i0 + 32 + wi];

  int r0 = (w & 1) * 32;
  int c0 = (w >> 1) * (COL_T * 16);
  f32x4 acc[2][COL_T];
#pragma unroll
  for (int rr = 0; rr < 2; ++rr)
#pragma unroll
    for (int cc = 0; cc < COL_T; ++cc)
#pragma unroll
      for (int k = 0; k < 4; ++k) acc[rr][cc][k] = 0.f;

  // prefetch chunk 0 globals
  uint4 hpre[F / 32];
  ull_t mkA, mkB;
  float4 edLo, edHi;
#pragma unroll
  for (int p = 0; p < F / 32; ++p)
    hpre[p] = *(const uint4*)&hT[(size_t)(hd * F + p * 32 + wi) * NN + jg * 8];
  mkA = mask[(size_t)(i0 + wi) * 64];
  mkB = mask[(size_t)(i0 + 32 + wi) * 64];
  edLo = *(const float4*)&ed[hd * NN + jg * 8];
  edHi = *(const float4*)&ed[hd * NN + jg * 8 + 4];

  for (int jc = 0; jc < NN / 64; ++jc) {
    __syncthreads();  // previous MFMA phase done; LDS free
    // ---- stage B (hT chunk) ----
#pragma unroll
    for (int p = 0; p < F / 32; ++p)
      *(uint4*)&lds[BOFF + (p * 32 + wi) * 72 + jg * 8] = hpre[p];
    // ---- generate A (P weights, 8 consecutive j per thread, 2 rows) ----
    float edv[8] = {edLo.x, edLo.y, edLo.z, edLo.w, edHi.x, edHi.y, edHi.z, edHi.w};
    s16x8 wA, wB;
#pragma unroll
    for (int k = 0; k < 8; ++k) {
      float zA = lrelu(esA + edv[k]);
      float vA = ((mkA >> (jg * 8 + k)) & 1ull) ? __expf(zA - mA) * liA : 0.f;
      wA[k] = (short)f2bf(vA);
      float zB = lrelu(esB + edv[k]);
      float vB = ((mkB >> (jg * 8 + k)) & 1ull) ? __expf(zB - mB) * liB : 0.f;
      wB[k] = (short)f2bf(vB);
    }
    *(s16x8*)&lds[wi * 72 + jg * 8] = wA;
    *(s16x8*)&lds[(32 + wi) * 72 + jg * 8] = wB;
    // ---- prefetch next chunk (overlaps with MFMA phase) ----
    if (jc + 1 < NN / 64) {
      int j0 = (jc + 1) * 64;
#pragma unroll
      for (int p = 0; p < F / 32; ++p)
        hpre[p] = *(const uint4*)&hT[(size_t)(hd * F + p * 32 + wi) * NN + j0 + jg * 8];
      mkA = mask[(size_t)(i0 + wi) * 64 + jc + 1];
      mkB = mask[(size_t)(i0 + 32 + wi) * 64 + jc + 1];
      edLo = *(const float4*)&ed[hd * NN + j0 + jg * 8];
      edHi = *(const float4*)&ed[hd * NN + j0 + jg * 8 + 4];
    }
    __syncthreads();  // staged data visible
    // ---- MFMA phase: K=64 as 2 ksteps of 32 ----
#pragma unroll
    for (int s = 0; s < 2; ++s) {
      s16x8 a0 = *(s16x8*)&lds[(r0 + nn) * 72 + s * 32 + q * 8];
      s16x8 a1 = *(s16x8*)&lds[(r0 + 16 + nn) * 72 + s * 32 + q * 8];
#pragma unroll
      for (int cc = 0; cc < COL_T; ++cc) {
        s16x8 b = *(s16x8*)&lds[BOFF + (c0 + cc * 16 + nn) * 72 + s * 32 + q * 8];
        acc[0][cc] = __builtin_amdgcn_mfma_f32_16x16x32_bf16(a0, b, acc[0][cc], 0, 0, 0);
        acc[1][cc] = __builtin_amdgcn_mfma_f32_16x16x32_bf16(a1, b, acc[1][cc], 0, 0, 0);
      }
    }
  }
  // ---- epilogue: C/D layout col=lane&15, row=quad*4+reg ----
#pragma unroll
  for (int rr = 0; rr < 2; ++rr)
#pragma unroll
    for (int cc = 0; cc < COL_T; ++cc)
#pragma unroll
      for (int reg = 0; reg < 4; ++reg) {
        int gi = i0 + r0 + rr * 16 + q * 4 + reg;
        int gf = hd * F + c0 + cc * 16 + nn;
        sto(&out[(size_t)gi * (H4 * F) + gf], acc[rr][cc][reg]);
      }
}

// ---------------- per-column mean / inv-std ----------------
__global__ __launch_bounds__(256) void k_colstats(const float* __restrict__ y,
                                                  float* __restrict__ stats, int C) {
  int c = blockIdx.x, tid = threadIdx.x;
  float s = 0.f, s2 = 0.f;
  for (int r = tid; r < NN; r += 256) {
    float v = y[(size_t)r * C + c];
    s += v;
    s2 += v * v;
  }
  __shared__ float sh[256], sh2[256];
  sh[tid] = s; sh2[tid] = s2;
  __syncthreads();
  for (int off = 128; off; off >>= 1) {
    if (tid < off) { sh[tid] += sh[tid + off]; sh2[tid] += sh2[tid + off]; }
    __syncthreads();
  }
  if (tid == 0) {
    float mean = sh[0] * (1.f / NN);
    float var = sh2[0] * (1.f / NN) - mean * mean;
    stats[c] = mean;
    stats[C + c] = rsqrtf(fmaxf(var, 0.f) + 1e-5f);
  }
}

// ---------------- BN + ELU ----------------
__global__ __launch_bounds__(256) void k_bn_elu(const float* __restrict__ y,
                                                const float* __restrict__ stats,
                                                const float* __restrict__ gamma,
                                                const float* __restrict__ beta,
                                                float* __restrict__ o, int C, int total) {
  int idx = blockIdx.x * 256 + threadIdx.x;
  if (idx >= total) return;
  int c = idx % C;
  float v = (y[idx] - stats[c]) * stats[C + c] * gamma[c] + beta[c];
  v = v > 0.f ? v : (__expf(v) - 1.f);
  o[idx] = v;
}

extern "C" void kernel_launch(void* const* d_in, const int* in_sizes, int n_in,
                              void* d_out, int out_size, void* d_ws, size_t ws_size,
                              hipStream_t stream) {
  (void)in_sizes; (void)n_in; (void)out_size; (void)ws_size;
  const float* x   = (const float*)d_in[0];
  const int*   adj = (const int*)d_in[1];
  const float* W1  = (const float*)d_in[2];
  const float* a1s = (const float*)d_in[3];
  const float* a1d = (const float*)d_in[4];
  const float* lw1 = (const float*)d_in[5];
  const float* lb1 = (const float*)d_in[6];
  const float* g1  = (const float*)d_in[7];
  const float* be1 = (const float*)d_in[8];
  const float* W2  = (const float*)d_in[9];
  const float* a2s = (const float*)d_in[10];
  const float* a2d = (const float*)d_in[11];
  const float* lw2 = (const float*)d_in[12];
  const float* lb2 = (const float*)d_in[13];
  const float* g2  = (const float*)d_in[14];
  const float* be2 = (const float*)d_in[15];
  float* out = (float*)d_out;

  // ---- workspace (peak 18.6 MB, same as proven R3 layout), liveness-checked ----
  char* w = (char*)d_ws;
  const size_t MB = 1u << 20;
  ull_t* mask = (ull_t*)(w + 0);            // [0,2) whole session
  float*    h1  = (float*)(w + 2 * MB);     // [2,10) f32; dead after scores1/transpose1
  float*    y1  = (float*)(w + 2 * MB);     // [2,3)  overlay (gemm2 out; h1 dead)
  float*    x2  = (float*)(w + 3 * MB);     // [3,4)
  float*    h2  = (float*)(w + 4 * MB);     // [4,6)  dead after scores2/transpose2
  ushort_t* hT2 = (ushort_t*)(w + 6 * MB);  // [6,7)  bf16 h2^T
  float*    x3  = (float*)(w + 7 * MB);     // [7,9)
  float*    y2  = (float*)(w + 9 * MB);     // [9,9.25)
  ushort_t* hT1 = (ushort_t*)(w + 10 * MB); // [10,14) bf16 h1^T; dead after agg1
  bf16*     x1  = (bf16*)(w + 14 * MB);     // [14,18) bf16; dead after gemm2
  float* es1 = (float*)(w + 18 * MB);       // aux
  float* ed1 = es1 + 16384;
  float* m1  = ed1 + 16384;
  float* li1 = m1 + 16384;
  float* es2 = li1 + 16384;
  float* ed2 = es2 + 16384;
  float* m2  = ed2 + 16384;
  float* li2 = m2 + 16384;
  float* st1 = li2 + 16384;
  float* st2 = st1 + 256;

  k_mask<<<NN, 256, 0, stream>>>(adj, mask);

  // ---- layer 1 GAT ----
  k_gemm<float><<<dim3(8, 64), 256, 0, stream>>>(x, W1, nullptr, h1, NN, 512, 512);
  k_transpose<512><<<dim3(64, 32), 256, 0, stream>>>(h1, hT1);
  k_scores<128><<<(NN * H4) / 256, 256, 0, stream>>>(h1, a1s, a1d, es1, ed1);
  k_stats<<<NN, 256, 0, stream>>>(es1, ed1, mask, m1, li1);
  k_agg_mfma<128, 4, bf16><<<dim3(64, 4), 256, 0, stream>>>(hT1, es1, ed1, m1, li1, mask, x1);

  // ---- linear + BN + ELU ----
  k_gemm<bf16><<<dim3(1, 64), 256, 0, stream>>>(x1, lw1, lb1, y1, NN, 512, 64);
  k_colstats<<<64, 256, 0, stream>>>(y1, st1, 64);
  k_bn_elu<<<(NN * 64) / 256, 256, 0, stream>>>(y1, st1, g1, be1, x2, 64, NN * 64);

  // ---- layer 2 GAT ----
  k_gemm<float><<<dim3(2, 64), 256, 0, stream>>>(x2, W2, nullptr, h2, NN, 64, 128);
  k_transpose<128><<<dim3(64, 8), 256, 0, stream>>>(h2, hT2);
  k_scores<32><<<(NN * H4) / 256, 256, 0, stream>>>(h2, a2s, a2d, es2, ed2);
  k_stats<<<NN, 256, 0, stream>>>(es2, ed2, mask, m2, li2);
  k_agg_mfma<32, 1, float><<<dim3(64, 4), 256, 0, stream>>>(hT2, es2, ed2, m2, li2, mask, x3);

  // ---- final linear + BN + ELU ----
  k_gemm<float><<<dim3(1, 64), 256, 0, stream>>>(x3, lw2, lb2, y2, NN, 128, 16);
  k_colstats<<<16, 256, 0, stream>>>(y2, st2, 16);
  k_bn_elu<<<(NN * 16) / 256, 256, 0, stream>>>(y2, st2, g2, be2, out, 16, NN * 16);
}